// Round 1
// baseline (1382.402 us; speedup 1.0000x reference)
//
#include <hip/hip_runtime.h>
#include <hip/hip_bf16.h>

// Problem dims (fixed by setup_inputs)
constexpr int Bb = 2, Hh = 32, Ss = 1024, Dd = 64;

// ---------------------------------------------------------------------------
// Sequential DPLR scan. One block (256 thr = 4 waves) per (b,h).
// lane = v-column (64). Wave w owns k-rows [16w, 16w+16); state h[k][v] lives
// in 16 VGPRs per lane. Per-k multipliers are wave-uniform -> scalar loads.
// Two LDS reduction rounds per step: ah = a^T h (pre-update), o = q^T h (post).
// ---------------------------------------------------------------------------
__global__ __launch_bounds__(256) void dplr_scan(
    const float* __restrict__ qp, const float* __restrict__ kp,
    const float* __restrict__ vp, const float* __restrict__ ap,
    const float* __restrict__ bp, const float* __restrict__ gkp,
    float* __restrict__ obuf)
{
    const int bh   = blockIdx.x;
    const int lane = (int)(threadIdx.x & 63u);
    const int w    = __builtin_amdgcn_readfirstlane((int)(threadIdx.x >> 6));
    const int kb   = w << 4;

    __shared__ float red_a[4][64];
    __shared__ float red_o[4][64];

    const size_t base = (size_t)bh * Ss * Dd;

    float h[16];
#pragma unroll
    for (int j = 0; j < 16; ++j) h[j] = 0.f;

    for (int t = 0; t < Ss; ++t) {
        const size_t off = base + (size_t)t * Dd;
        const float vv = vp[off + lane];          // vector load, coalesced

        // ---- partial a^T h over this wave's k-chunk (scalars wave-uniform)
        float ah0 = 0.f, ah1 = 0.f, ah2 = 0.f, ah3 = 0.f;
#pragma unroll
        for (int j = 0; j < 16; j += 4) {
            const float a0 = ap[off + kb + j + 0];
            const float a1 = ap[off + kb + j + 1];
            const float a2 = ap[off + kb + j + 2];
            const float a3 = ap[off + kb + j + 3];
            ah0 = fmaf(a0, h[j + 0], ah0);
            ah1 = fmaf(a1, h[j + 1], ah1);
            ah2 = fmaf(a2, h[j + 2], ah2);
            ah3 = fmaf(a3, h[j + 3], ah3);
        }
        red_a[w][lane] = (ah0 + ah1) + (ah2 + ah3);
        __syncthreads();
        const float ah = (red_a[0][lane] + red_a[1][lane]) +
                         (red_a[2][lane] + red_a[3][lane]);

        // ---- state update + partial q^T h_new
        float op0 = 0.f, op1 = 0.f;
#pragma unroll
        for (int j = 0; j < 16; ++j) {
            const float wj = __expf(gkp[off + kb + j]);   // wave-uniform
            const float bj = bp[off + kb + j];
            const float kj = kp[off + kb + j];
            const float qj = qp[off + kb + j];
            const float x  = fmaf(bj, ah, kj * vv);
            h[j] = fmaf(wj, h[j], x);
            if (j & 1) op1 = fmaf(qj, h[j], op1);
            else       op0 = fmaf(qj, h[j], op0);
        }
        red_o[w][lane] = op0 + op1;
        __syncthreads();
        if (w == 0) {
            obuf[off + lane] = (red_o[0][lane] + red_o[1][lane]) +
                               (red_o[2][lane] + red_o[3][lane]);
        }
        // next iteration's red_a writes are separated from this iteration's
        // red_a reads by the second barrier; red_o writes by the first. safe.
    }
}

// ---------------------------------------------------------------------------
// Epilogue: per (b,s,h) group of Dv=64: GroupNorm + (q.k.r_k)*v correction,
// gated by g. One wave per group, lane = v. Shuffle-reduce over 64 lanes.
// ---------------------------------------------------------------------------
__global__ __launch_bounds__(256) void epilogue(
    const float* __restrict__ obuf, const float* __restrict__ qp,
    const float* __restrict__ kp,  const float* __restrict__ vp,
    const float* __restrict__ rk,  const float* __restrict__ gp,
    const float* __restrict__ sc,  const float* __restrict__ bi,
    float* __restrict__ out)
{
    const int lane = (int)(threadIdx.x & 63u);
    const int gid  = blockIdx.x * 4 + (int)(threadIdx.x >> 6); // (b*S+s)*H + h
    const int hh   = gid & (Hh - 1);
    const int bs   = gid >> 5;            // b*S + s
    const int b    = bs >> 10;            // S = 1024
    const int s    = bs & (Ss - 1);

    const size_t ooff = ((size_t)(b * Hh + hh) * Ss + s) * Dd + lane;
    const float o  = obuf[ooff];
    const float qv = qp[ooff];
    const float kv = kp[ooff];
    const float vv = vp[ooff];
    const float r  = rk[hh * Dd + lane];

    float s1 = o, s2 = o * o, s3 = qv * kv * r;
#pragma unroll
    for (int m = 32; m >= 1; m >>= 1) {
        s1 += __shfl_xor(s1, m, 64);
        s2 += __shfl_xor(s2, m, 64);
        s3 += __shfl_xor(s3, m, 64);
    }
    const float mu  = s1 * (1.f / 64.f);
    const float var = fmaf(-mu, mu, s2 * (1.f / 64.f));
    const float on  = (o - mu) * rsqrtf(var + 1e-5f);

    const size_t goff = (size_t)bs * (Hh * Dd) + hh * Dd + lane;
    out[goff] = (fmaf(on, sc[hh * Dd + lane], bi[hh * Dd + lane]) + s3 * vv) * gp[goff];
}

// ---------------------------------------------------------------------------
extern "C" void kernel_launch(void* const* d_in, const int* in_sizes, int n_in,
                              void* d_out, int out_size, void* d_ws, size_t ws_size,
                              hipStream_t stream)
{
    const float* q   = (const float*)d_in[0];
    const float* k   = (const float*)d_in[1];
    const float* v   = (const float*)d_in[2];
    const float* a   = (const float*)d_in[3];
    const float* b   = (const float*)d_in[4];
    const float* gk  = (const float*)d_in[5];
    const float* r_k = (const float*)d_in[6];
    const float* g   = (const float*)d_in[7];
    const float* gns = (const float*)d_in[8];
    const float* gnb = (const float*)d_in[9];
    float* out  = (float*)d_out;
    float* obuf = (float*)d_ws;   // [B,H,S,Dv] fp32 scratch = 16 MiB

    dplr_scan<<<dim3(Bb * Hh), dim3(256), 0, stream>>>(q, k, v, a, b, gk, obuf);

    const int groups = Bb * Ss * Hh;      // 65536 waves
    epilogue<<<dim3(groups / 4), dim3(256), 0, stream>>>(
        obuf, q, k, v, r_k, g, gns, gnb, out);
}

// Round 2
// 585.756 us; speedup vs baseline: 2.3600x; 2.3600x over previous
//
#include <hip/hip_runtime.h>
#include <hip/hip_bf16.h>

constexpr int Bb = 2, Hh = 32, Ss = 1024, Dd = 64;
constexpr int SEG = 64;          // segment length
constexpr int NP  = Ss / SEG;    // 16 segments
constexpr int NBH = Bb * Hh;     // 64

// ---------------------------------------------------------------------------
// Phase 1: per (bh,p) segment compute local-scan result.
//   mode 0 (blockIdx.y==0): G_p = segment scan from zero init (with k v^T input)
//   mode 1 (blockIdx.y==1): M_p = product of A_t over segment (identity init, no input)
// One wave (64 threads). lane = v-column; all 64 k-rows of state in VGPRs.
// exp(gk) precomputed into LDS at segment start (full-lane parallel).
// ---------------------------------------------------------------------------
__global__ __launch_bounds__(64) void scan_seg(
    const float* __restrict__ kp, const float* __restrict__ vp,
    const float* __restrict__ ap, const float* __restrict__ bp,
    const float* __restrict__ gkp,
    float* __restrict__ Gbuf, float* __restrict__ Mbuf)
{
    const int lane = (int)threadIdx.x;
    const int bid  = (int)blockIdx.x;           // bh*NP + p
    const int mode = (int)blockIdx.y;           // 0 = G, 1 = M
    const size_t segbase = (size_t)bid * (SEG * Dd);  // = bh*S*D + p*SEG*D

    __shared__ float wbuf[SEG * Dd];            // 16 KiB: exp(gk) for the segment
    {
        const float4* g4 = (const float4*)(gkp + segbase);
        float4* w4 = (float4*)wbuf;
        for (int i = lane; i < SEG * Dd / 4; i += 64) {
            float4 g = g4[i], e;
            e.x = __expf(g.x); e.y = __expf(g.y);
            e.z = __expf(g.z); e.w = __expf(g.w);
            w4[i] = e;
        }
    }
    __syncthreads();

    float h[64];
#pragma unroll
    for (int j = 0; j < 64; ++j) h[j] = mode ? ((j == lane) ? 1.f : 0.f) : 0.f;

    for (int tl = 0; tl < SEG; ++tl) {
        const size_t off = segbase + (size_t)tl * Dd;
        float u = 0.f;
        if (!mode) u = vp[off + lane];          // per-lane vector load (G only)

        float ah0 = 0.f, ah1 = 0.f, ah2 = 0.f, ah3 = 0.f;
#pragma unroll
        for (int j = 0; j < 64; j += 4) {       // a[j] wave-uniform -> s_load
            ah0 = fmaf(ap[off + j + 0], h[j + 0], ah0);
            ah1 = fmaf(ap[off + j + 1], h[j + 1], ah1);
            ah2 = fmaf(ap[off + j + 2], h[j + 2], ah2);
            ah3 = fmaf(ap[off + j + 3], h[j + 3], ah3);
        }
        const float ah = (ah0 + ah1) + (ah2 + ah3);

        const float4* wrow = (const float4*)(wbuf + tl * Dd);
#pragma unroll
        for (int jj = 0; jj < 16; ++jj) {
            const float4 w4 = wrow[jj];
            const int j = jj * 4;
            h[j + 0] = fmaf(w4.x, h[j + 0], fmaf(bp[off + j + 0], ah, kp[off + j + 0] * u));
            h[j + 1] = fmaf(w4.y, h[j + 1], fmaf(bp[off + j + 1], ah, kp[off + j + 1] * u));
            h[j + 2] = fmaf(w4.z, h[j + 2], fmaf(bp[off + j + 2], ah, kp[off + j + 2] * u));
            h[j + 3] = fmaf(w4.w, h[j + 3], fmaf(bp[off + j + 3], ah, kp[off + j + 3] * u));
        }
    }

    float* dst = (mode ? Mbuf : Gbuf) + (size_t)bid * 4096;
#pragma unroll
    for (int j = 0; j < 64; ++j) dst[j * 64 + lane] = h[j];   // [j][c] coalesced
}

// ---------------------------------------------------------------------------
// Phase 2: per bh, sequentially fold SW_p = M_p * SW_{p-1} + G_p, p = 1..15.
// SW_p overwrites Gbuf slot p (slot 0 already holds SW_0 = G_0).
// 4 waves: lane = column c, wave w owns rows [16w,16w+16). Ht is the running
// state transposed [c][m] (pad 65 -> conflict-free scalar reads).
// ---------------------------------------------------------------------------
__global__ __launch_bounds__(256) void combine(
    const float* __restrict__ Mbuf, float* __restrict__ Gbuf)
{
    const int bh   = (int)blockIdx.x;
    const int tid  = (int)threadIdx.x;
    const int lane = tid & 63;
    const int w    = __builtin_amdgcn_readfirstlane(tid >> 6);

    __shared__ float Ht[64][65];                // [c][m]
    for (int i = tid; i < 4096; i += 256)       // i = m*64 + c, coalesced read
        Ht[i & 63][i >> 6] = Gbuf[(size_t)(bh * NP) * 4096 + i];
    __syncthreads();

    for (int p = 1; p < NP; ++p) {
        const float* Mp = Mbuf + (size_t)(bh * NP + p) * 4096;
        float*       Gp = Gbuf + (size_t)(bh * NP + p) * 4096;

        float hc[64];                           // my column of SW_{p-1}
#pragma unroll
        for (int m = 0; m < 64; ++m) hc[m] = Ht[lane][m];
        __syncthreads();                        // reads done before overwrite

        float acc[16];
#pragma unroll
        for (int r = 0; r < 16; ++r) acc[r] = Gp[(w * 16 + r) * 64 + lane];

#pragma unroll
        for (int r = 0; r < 16; ++r) {
            const int row = (w * 16 + r) * 64;  // M row, wave-uniform -> s_load
            float s0 = 0.f, s1 = 0.f, s2 = 0.f, s3 = 0.f;
#pragma unroll
            for (int m = 0; m < 64; m += 4) {
                s0 = fmaf(Mp[row + m + 0], hc[m + 0], s0);
                s1 = fmaf(Mp[row + m + 1], hc[m + 1], s1);
                s2 = fmaf(Mp[row + m + 2], hc[m + 2], s2);
                s3 = fmaf(Mp[row + m + 3], hc[m + 3], s3);
            }
            acc[r] += (s0 + s1) + (s2 + s3);
        }
#pragma unroll
        for (int r = 0; r < 16; ++r) {
            Gp[(w * 16 + r) * 64 + lane] = acc[r];   // SW_p out (coalesced)
            Ht[lane][w * 16 + r] = acc[r];           // update running state
        }
        __syncthreads();
    }
}

// ---------------------------------------------------------------------------
// Phase 3: replay each segment from its true incoming state SW_{p-1}, compute
// o_t = h_t^T q_t, write raw o into d_out at its final [B,S,H,Dv] position.
// ---------------------------------------------------------------------------
__global__ __launch_bounds__(64) void scan_out(
    const float* __restrict__ qp, const float* __restrict__ kp,
    const float* __restrict__ vp, const float* __restrict__ ap,
    const float* __restrict__ bp, const float* __restrict__ gkp,
    const float* __restrict__ Gbuf, float* __restrict__ out)
{
    const int lane = (int)threadIdx.x;
    const int bid  = (int)blockIdx.x;           // bh*NP + p
    const int p    = bid & (NP - 1);
    const int bh   = bid >> 4;
    const size_t segbase = (size_t)bid * (SEG * Dd);

    __shared__ float wbuf[SEG * Dd];
    {
        const float4* g4 = (const float4*)(gkp + segbase);
        float4* w4 = (float4*)wbuf;
        for (int i = lane; i < SEG * Dd / 4; i += 64) {
            float4 g = g4[i], e;
            e.x = __expf(g.x); e.y = __expf(g.y);
            e.z = __expf(g.z); e.w = __expf(g.w);
            w4[i] = e;
        }
    }
    __syncthreads();

    float h[64];
    if (p) {
        const float* sw = Gbuf + (size_t)(bid - 1) * 4096;   // SW_{p-1}
#pragma unroll
        for (int j = 0; j < 64; ++j) h[j] = sw[j * 64 + lane];
    } else {
#pragma unroll
        for (int j = 0; j < 64; ++j) h[j] = 0.f;
    }

    const int b = bh >> 5, hh = bh & (Hh - 1);

    for (int tl = 0; tl < SEG; ++tl) {
        const size_t off = segbase + (size_t)tl * Dd;
        const float u = vp[off + lane];

        float ah0 = 0.f, ah1 = 0.f, ah2 = 0.f, ah3 = 0.f;
#pragma unroll
        for (int j = 0; j < 64; j += 4) {
            ah0 = fmaf(ap[off + j + 0], h[j + 0], ah0);
            ah1 = fmaf(ap[off + j + 1], h[j + 1], ah1);
            ah2 = fmaf(ap[off + j + 2], h[j + 2], ah2);
            ah3 = fmaf(ap[off + j + 3], h[j + 3], ah3);
        }
        const float ah = (ah0 + ah1) + (ah2 + ah3);

        const float4* wrow = (const float4*)(wbuf + tl * Dd);
        float o0 = 0.f, o1 = 0.f, o2 = 0.f, o3 = 0.f;
#pragma unroll
        for (int jj = 0; jj < 16; ++jj) {
            const float4 w4 = wrow[jj];
            const int j = jj * 4;
            h[j + 0] = fmaf(w4.x, h[j + 0], fmaf(bp[off + j + 0], ah, kp[off + j + 0] * u));
            o0 = fmaf(qp[off + j + 0], h[j + 0], o0);
            h[j + 1] = fmaf(w4.y, h[j + 1], fmaf(bp[off + j + 1], ah, kp[off + j + 1] * u));
            o1 = fmaf(qp[off + j + 1], h[j + 1], o1);
            h[j + 2] = fmaf(w4.z, h[j + 2], fmaf(bp[off + j + 2], ah, kp[off + j + 2] * u));
            o2 = fmaf(qp[off + j + 2], h[j + 2], o2);
            h[j + 3] = fmaf(w4.w, h[j + 3], fmaf(bp[off + j + 3], ah, kp[off + j + 3] * u));
            o3 = fmaf(qp[off + j + 3], h[j + 3], o3);
        }
        const int s = p * SEG + tl;
        out[(((size_t)b * Ss + s) * Hh + hh) * Dd + lane] = (o0 + o1) + (o2 + o3);
    }
}

// ---------------------------------------------------------------------------
// Epilogue: in-place on d_out. GroupNorm per (b,s,h) over Dv + correction +
// gate. One wave per group; lane = v. dot(q,k,r_k) folded into the butterfly.
// ---------------------------------------------------------------------------
__global__ __launch_bounds__(256) void epilogue(
    const float* __restrict__ qp, const float* __restrict__ kp,
    const float* __restrict__ vp, const float* __restrict__ rk,
    const float* __restrict__ gp, const float* __restrict__ sc,
    const float* __restrict__ bi, float* __restrict__ out)
{
    const int lane = (int)(threadIdx.x & 63u);
    const int gid  = (int)blockIdx.x * 4 + (int)(threadIdx.x >> 6); // (b*S+s)*H + h
    const int hh   = gid & (Hh - 1);
    const int bs   = gid >> 5;            // b*S + s
    const int b    = bs >> 10;
    const int s    = bs & (Ss - 1);

    const size_t ioff = ((size_t)(b * Hh + hh) * Ss + s) * Dd + lane; // [B,H,S,D]
    const float qv = qp[ioff];
    const float kv = kp[ioff];
    const float vv = vp[ioff];
    const float r  = rk[hh * Dd + lane];

    const size_t goff = (size_t)bs * (Hh * Dd) + hh * Dd + lane;      // [B,S,hid]
    const float o = out[goff];

    float s1 = o, s2 = o * o, s3 = qv * kv * r;
#pragma unroll
    for (int m = 32; m >= 1; m >>= 1) {
        s1 += __shfl_xor(s1, m, 64);
        s2 += __shfl_xor(s2, m, 64);
        s3 += __shfl_xor(s3, m, 64);
    }
    const float mu  = s1 * (1.f / 64.f);
    const float var = fmaf(-mu, mu, s2 * (1.f / 64.f));
    const float on  = (o - mu) * rsqrtf(var + 1e-5f);

    out[goff] = (fmaf(on, sc[hh * Dd + lane], bi[hh * Dd + lane]) + s3 * vv) * gp[goff];
}

// ---------------------------------------------------------------------------
extern "C" void kernel_launch(void* const* d_in, const int* in_sizes, int n_in,
                              void* d_out, int out_size, void* d_ws, size_t ws_size,
                              hipStream_t stream)
{
    const float* q   = (const float*)d_in[0];
    const float* k   = (const float*)d_in[1];
    const float* v   = (const float*)d_in[2];
    const float* a   = (const float*)d_in[3];
    const float* b   = (const float*)d_in[4];
    const float* gk  = (const float*)d_in[5];
    const float* r_k = (const float*)d_in[6];
    const float* g   = (const float*)d_in[7];
    const float* gns = (const float*)d_in[8];
    const float* gnb = (const float*)d_in[9];
    float* out  = (float*)d_out;
    float* Gbuf = (float*)d_ws;     // [NBH][NP][64][64] = 16.78 MB (= round-1 safe size)
    float* Mbuf = (float*)d_out;    // M_p parked in d_out (exactly out_size), consumed
                                    // by combine before scan_out overwrites with o.

    scan_seg<<<dim3(NBH * NP, 2), dim3(64), 0, stream>>>(k, v, a, b, gk, Gbuf, Mbuf);
    combine <<<dim3(NBH),        dim3(256), 0, stream>>>(Mbuf, Gbuf);
    scan_out<<<dim3(NBH * NP),   dim3(64), 0, stream>>>(q, k, v, a, b, gk, Gbuf, out);
    epilogue<<<dim3(Bb * Ss * Hh / 4), dim3(256), 0, stream>>>(
        q, k, v, r_k, g, gns, gnb, out);
}

// Round 3
// 443.806 us; speedup vs baseline: 3.1149x; 1.3198x over previous
//
#include <hip/hip_runtime.h>
#include <hip/hip_bf16.h>

constexpr int Bb = 2, Hh = 32, Ss = 1024, Dd = 64;
constexpr int NBH = Bb * Hh;     // 64
constexpr int CH  = 16;          // LDS staging chunk (steps)

// M-slot indirection: slots p < nplo live in bufA, the rest in bufB.
__device__ __forceinline__ float* m_slot(float* A, float* B, int nplo,
                                         int bh, int p, int np) {
    return (p < nplo) ? A + ((size_t)bh * nplo + p) * 4096
                      : B + ((size_t)bh * (np - nplo) + (p - nplo)) * 4096;
}

// ---------------------------------------------------------------------------
// Phase 1: per (bh,p) segment: wave0 computes G_p (zero-init local scan),
// wave1 computes M_p (identity-init homogeneous propagation). Both waves share
// LDS staging of a,b,k,exp(gk),v in CH-step chunks. lane = column; the 64
// k-rows of the state live in VGPRs; all per-k scalars are LDS broadcasts.
// ---------------------------------------------------------------------------
template<int SEG>
__global__ __launch_bounds__(128) void scan_seg(
    const float* __restrict__ kp, const float* __restrict__ vp,
    const float* __restrict__ ap, const float* __restrict__ bp,
    const float* __restrict__ gkp,
    float* __restrict__ Gbuf, float* MbufA, float* MbufB, int nplo)
{
    constexpr int NP = Ss / SEG;
    const int tid  = (int)threadIdx.x;
    const int lane = tid & 63;
    const int wv   = __builtin_amdgcn_readfirstlane(tid >> 6);  // 0=G, 1=M
    const int bid  = (int)blockIdx.x;                 // bh*NP + p
    const size_t segbase = (size_t)bid * (SEG * Dd);

    __shared__ float lds[5 * CH * 64];                // 20 KiB
    float* la = lds;
    float* lb = lds + 1 * CH * 64;
    float* lk = lds + 2 * CH * 64;
    float* lw = lds + 3 * CH * 64;
    float* lv = lds + 4 * CH * 64;

    float h[64];
#pragma unroll
    for (int j = 0; j < 64; ++j) h[j] = wv ? ((j == lane) ? 1.f : 0.f) : 0.f;

    for (int c0 = 0; c0 < SEG; c0 += CH) {
        // ---- stage CH steps of all 5 streams (128 threads, float4)
        {
            const size_t gb = segbase + (size_t)c0 * 64;
            const float4* a4 = (const float4*)(ap + gb);
            const float4* b4 = (const float4*)(bp + gb);
            const float4* k4 = (const float4*)(kp + gb);
            const float4* g4 = (const float4*)(gkp + gb);
            const float4* v4 = (const float4*)(vp + gb);
            float4* LA = (float4*)la; float4* LB = (float4*)lb;
            float4* LK = (float4*)lk; float4* LW = (float4*)lw;
            float4* LV = (float4*)lv;
#pragma unroll
            for (int i = 0; i < CH * 16; i += 128) {
                const int idx = i + tid;
                LA[idx] = a4[idx];
                LB[idx] = b4[idx];
                LK[idx] = k4[idx];
                float4 g = g4[idx], e;
                e.x = __expf(g.x); e.y = __expf(g.y);
                e.z = __expf(g.z); e.w = __expf(g.w);
                LW[idx] = e;
                LV[idx] = v4[idx];
            }
        }
        __syncthreads();

        if (wv == 0) {                                // ---- G scan
            for (int tl = 0; tl < CH; ++tl) {
                const float u = lv[tl * 64 + lane];
                const float4* ar = (const float4*)(la + tl * 64);
                const float4* br = (const float4*)(lb + tl * 64);
                const float4* kr = (const float4*)(lk + tl * 64);
                const float4* wr = (const float4*)(lw + tl * 64);
                float s0 = 0.f, s1 = 0.f, s2 = 0.f, s3 = 0.f;
#pragma unroll
                for (int jj = 0; jj < 16; ++jj) {
                    const float4 a4 = ar[jj];
                    s0 = fmaf(a4.x, h[4*jj+0], s0);
                    s1 = fmaf(a4.y, h[4*jj+1], s1);
                    s2 = fmaf(a4.z, h[4*jj+2], s2);
                    s3 = fmaf(a4.w, h[4*jj+3], s3);
                }
                const float ah = (s0 + s1) + (s2 + s3);
#pragma unroll
                for (int jj = 0; jj < 16; ++jj) {
                    const float4 b4 = br[jj], k4 = kr[jj], w4 = wr[jj];
                    h[4*jj+0] = fmaf(w4.x, h[4*jj+0], fmaf(b4.x, ah, k4.x * u));
                    h[4*jj+1] = fmaf(w4.y, h[4*jj+1], fmaf(b4.y, ah, k4.y * u));
                    h[4*jj+2] = fmaf(w4.z, h[4*jj+2], fmaf(b4.z, ah, k4.z * u));
                    h[4*jj+3] = fmaf(w4.w, h[4*jj+3], fmaf(b4.w, ah, k4.w * u));
                }
            }
        } else {                                      // ---- M scan (u = 0)
            for (int tl = 0; tl < CH; ++tl) {
                const float4* ar = (const float4*)(la + tl * 64);
                const float4* br = (const float4*)(lb + tl * 64);
                const float4* wr = (const float4*)(lw + tl * 64);
                float s0 = 0.f, s1 = 0.f, s2 = 0.f, s3 = 0.f;
#pragma unroll
                for (int jj = 0; jj < 16; ++jj) {
                    const float4 a4 = ar[jj];
                    s0 = fmaf(a4.x, h[4*jj+0], s0);
                    s1 = fmaf(a4.y, h[4*jj+1], s1);
                    s2 = fmaf(a4.z, h[4*jj+2], s2);
                    s3 = fmaf(a4.w, h[4*jj+3], s3);
                }
                const float ah = (s0 + s1) + (s2 + s3);
#pragma unroll
                for (int jj = 0; jj < 16; ++jj) {
                    const float4 b4 = br[jj], w4 = wr[jj];
                    h[4*jj+0] = fmaf(w4.x, h[4*jj+0], b4.x * ah);
                    h[4*jj+1] = fmaf(w4.y, h[4*jj+1], b4.y * ah);
                    h[4*jj+2] = fmaf(w4.z, h[4*jj+2], b4.z * ah);
                    h[4*jj+3] = fmaf(w4.w, h[4*jj+3], b4.w * ah);
                }
            }
        }
        __syncthreads();
    }

    const int p  = bid & (NP - 1);
    const int bh = bid / NP;
    float* dst = (wv == 0) ? Gbuf + (size_t)bid * 4096
                           : m_slot(MbufA, MbufB, nplo, bh, p, NP);
#pragma unroll
    for (int j = 0; j < 64; ++j) dst[j * 64 + lane] = h[j];
}

// ---------------------------------------------------------------------------
// Phase 2: SW_p = M_p * SW_{p-1} + G_p, sequential over p, but split over
// 4 column-blocks per bh (columns independent) -> NBH*4 = 256 blocks.
// Thread t: col = c0+(t&15), rows 4*(t>>4)..+3. SW column slice in LDS.
// ---------------------------------------------------------------------------
template<int NP>
__global__ __launch_bounds__(256) void combine(
    const float* MbufA, const float* MbufB, int nplo, float* __restrict__ Gbuf)
{
    const int bh  = (int)blockIdx.x >> 2;
    const int cb  = (int)blockIdx.x & 3;
    const int c0  = cb * 16;
    const int tid = (int)threadIdx.x;
    const int cl  = tid & 15;           // local col
    const int c   = c0 + cl;
    const int r0  = (tid >> 4) * 4;

    __shared__ float SW[64][16];
    for (int i = tid; i < 1024; i += 256)
        SW[i >> 4][i & 15] = Gbuf[(size_t)bh * NP * 4096 + (i >> 4) * 64 + c0 + (i & 15)];
    __syncthreads();

    for (int p = 1; p < NP; ++p) {
        const float* Mp = m_slot((float*)MbufA, (float*)MbufB, nplo, bh, p, NP);
        float* Gp = Gbuf + ((size_t)bh * NP + p) * 4096;

        float acc[4];
#pragma unroll
        for (int r = 0; r < 4; ++r) acc[r] = Gp[(r0 + r) * 64 + c];

#pragma unroll
        for (int r = 0; r < 4; ++r) {
            const float4* mr = (const float4*)(Mp + (r0 + r) * 64);
            float s0 = 0.f, s1 = 0.f, s2 = 0.f, s3 = 0.f;
#pragma unroll
            for (int m4 = 0; m4 < 16; ++m4) {
                const float4 m = mr[m4];
                s0 = fmaf(m.x, SW[4*m4+0][cl], s0);
                s1 = fmaf(m.y, SW[4*m4+1][cl], s1);
                s2 = fmaf(m.z, SW[4*m4+2][cl], s2);
                s3 = fmaf(m.w, SW[4*m4+3][cl], s3);
            }
            acc[r] += (s0 + s1) + (s2 + s3);
        }
#pragma unroll
        for (int r = 0; r < 4; ++r) Gp[(r0 + r) * 64 + c] = acc[r];
        __syncthreads();
#pragma unroll
        for (int r = 0; r < 4; ++r) SW[r0 + r][cl] = acc[r];
        __syncthreads();
    }
}

// ---------------------------------------------------------------------------
// Phase 3: replay segment p from SW_{p-1}, o_t = h_t^T q_t -> d_out [B,S,hid].
// One wave per segment; a,b,k,w,q staged in LDS per CH-step chunk; v via
// 1-step register prefetch from global.
// ---------------------------------------------------------------------------
template<int SEG>
__global__ __launch_bounds__(64) void scan_out(
    const float* __restrict__ qp, const float* __restrict__ kp,
    const float* __restrict__ vp, const float* __restrict__ ap,
    const float* __restrict__ bp, const float* __restrict__ gkp,
    const float* __restrict__ Gbuf, float* __restrict__ out)
{
    constexpr int NP = Ss / SEG;
    const int lane = (int)threadIdx.x;
    const int bid  = (int)blockIdx.x;                 // bh*NP + p
    const int p    = bid & (NP - 1);
    const int bh   = bid / NP;
    const size_t segbase = (size_t)bid * (SEG * Dd);

    __shared__ float lds[5 * CH * 64];                // a,b,k,w,q : 20 KiB
    float* la = lds;
    float* lb = lds + 1 * CH * 64;
    float* lk = lds + 2 * CH * 64;
    float* lw = lds + 3 * CH * 64;
    float* lq = lds + 4 * CH * 64;

    float h[64];
    if (p) {
        const float* sw = Gbuf + (size_t)(bid - 1) * 4096;
#pragma unroll
        for (int j = 0; j < 64; ++j) h[j] = sw[j * 64 + lane];
    } else {
#pragma unroll
        for (int j = 0; j < 64; ++j) h[j] = 0.f;
    }

    const int b = bh >> 5, hh = bh & (Hh - 1);
    float u = vp[segbase + lane];

    for (int c0 = 0; c0 < SEG; c0 += CH) {
        {
            const size_t gb = segbase + (size_t)c0 * 64;
            const float4* a4 = (const float4*)(ap + gb);
            const float4* b4 = (const float4*)(bp + gb);
            const float4* k4 = (const float4*)(kp + gb);
            const float4* g4 = (const float4*)(gkp + gb);
            const float4* q4 = (const float4*)(qp + gb);
            float4* LA = (float4*)la; float4* LB = (float4*)lb;
            float4* LK = (float4*)lk; float4* LW = (float4*)lw;
            float4* LQ = (float4*)lq;
#pragma unroll
            for (int i = 0; i < CH * 16; i += 64) {
                const int idx = i + lane;
                LA[idx] = a4[idx];
                LB[idx] = b4[idx];
                LK[idx] = k4[idx];
                float4 g = g4[idx], e;
                e.x = __expf(g.x); e.y = __expf(g.y);
                e.z = __expf(g.z); e.w = __expf(g.w);
                LW[idx] = e;
                LQ[idx] = q4[idx];
            }
        }
        __syncthreads();

        for (int tl = 0; tl < CH; ++tl) {
            const int t = c0 + tl;
            float u_next = 0.f;
            if (t + 1 < SEG) u_next = vp[segbase + (size_t)(t + 1) * 64 + lane];

            const float4* ar = (const float4*)(la + tl * 64);
            const float4* br = (const float4*)(lb + tl * 64);
            const float4* kr = (const float4*)(lk + tl * 64);
            const float4* wr = (const float4*)(lw + tl * 64);
            const float4* qr = (const float4*)(lq + tl * 64);

            float s0 = 0.f, s1 = 0.f, s2 = 0.f, s3 = 0.f;
#pragma unroll
            for (int jj = 0; jj < 16; ++jj) {
                const float4 a4 = ar[jj];
                s0 = fmaf(a4.x, h[4*jj+0], s0);
                s1 = fmaf(a4.y, h[4*jj+1], s1);
                s2 = fmaf(a4.z, h[4*jj+2], s2);
                s3 = fmaf(a4.w, h[4*jj+3], s3);
            }
            const float ah = (s0 + s1) + (s2 + s3);

            float o0 = 0.f, o1 = 0.f, o2 = 0.f, o3 = 0.f;
#pragma unroll
            for (int jj = 0; jj < 16; ++jj) {
                const float4 b4 = br[jj], k4 = kr[jj], w4 = wr[jj], q4 = qr[jj];
                h[4*jj+0] = fmaf(w4.x, h[4*jj+0], fmaf(b4.x, ah, k4.x * u));
                o0 = fmaf(q4.x, h[4*jj+0], o0);
                h[4*jj+1] = fmaf(w4.y, h[4*jj+1], fmaf(b4.y, ah, k4.y * u));
                o1 = fmaf(q4.y, h[4*jj+1], o1);
                h[4*jj+2] = fmaf(w4.z, h[4*jj+2], fmaf(b4.z, ah, k4.z * u));
                o2 = fmaf(q4.z, h[4*jj+2], o2);
                h[4*jj+3] = fmaf(w4.w, h[4*jj+3], fmaf(b4.w, ah, k4.w * u));
                o3 = fmaf(q4.w, h[4*jj+3], o3);
            }
            const int s = p * SEG + t;
            out[(((size_t)b * Ss + s) * Hh + hh) * Dd + lane] = (o0 + o1) + (o2 + o3);
            u = u_next;
        }
        __syncthreads();
    }
}

// ---------------------------------------------------------------------------
// Epilogue (unchanged from round 2): in-place GroupNorm + correction + gate.
// ---------------------------------------------------------------------------
__global__ __launch_bounds__(256) void epilogue(
    const float* __restrict__ qp, const float* __restrict__ kp,
    const float* __restrict__ vp, const float* __restrict__ rk,
    const float* __restrict__ gp, const float* __restrict__ sc,
    const float* __restrict__ bi, float* __restrict__ out)
{
    const int lane = (int)(threadIdx.x & 63u);
    const int gid  = (int)blockIdx.x * 4 + (int)(threadIdx.x >> 6);
    const int hh   = gid & (Hh - 1);
    const int bs   = gid >> 5;
    const int b    = bs >> 10;
    const int s    = bs & (Ss - 1);

    const size_t ioff = ((size_t)(b * Hh + hh) * Ss + s) * Dd + lane;
    const float qv = qp[ioff];
    const float kv = kp[ioff];
    const float vv = vp[ioff];
    const float r  = rk[hh * Dd + lane];

    const size_t goff = (size_t)bs * (Hh * Dd) + hh * Dd + lane;
    const float o = out[goff];

    float s1 = o, s2 = o * o, s3 = qv * kv * r;
#pragma unroll
    for (int m = 32; m >= 1; m >>= 1) {
        s1 += __shfl_xor(s1, m, 64);
        s2 += __shfl_xor(s2, m, 64);
        s3 += __shfl_xor(s3, m, 64);
    }
    const float mu  = s1 * (1.f / 64.f);
    const float var = fmaf(-mu, mu, s2 * (1.f / 64.f));
    const float on  = (o - mu) * rsqrtf(var + 1e-5f);

    out[goff] = (fmaf(on, sc[hh * Dd + lane], bi[hh * Dd + lane]) + s3 * vv) * gp[goff];
}

// ---------------------------------------------------------------------------
extern "C" void kernel_launch(void* const* d_in, const int* in_sizes, int n_in,
                              void* d_out, int out_size, void* d_ws, size_t ws_size,
                              hipStream_t stream)
{
    const float* q   = (const float*)d_in[0];
    const float* k   = (const float*)d_in[1];
    const float* v   = (const float*)d_in[2];
    const float* a   = (const float*)d_in[3];
    const float* b   = (const float*)d_in[4];
    const float* gk  = (const float*)d_in[5];
    const float* r_k = (const float*)d_in[6];
    const float* g   = (const float*)d_in[7];
    const float* gns = (const float*)d_in[8];
    const float* gnb = (const float*)d_in[9];
    float* out = (float*)d_out;
    float* ws  = (float*)d_ws;

    const size_t slotf   = 4096;                          // floats per matrix
    const size_t g32     = (size_t)NBH * 32 * slotf;      // G floats at NP=32
    const size_t need32  = g32 * 4 * 2;                   // 64 MiB
    const size_t need32b = g32 * 4 + (size_t)NBH * 16 * slotf * 4;  // 48 MiB

    if (ws_size >= need32) {
        // NP=32; G in ws[0..), M in ws[g32..)
        float* G  = ws;
        float* MA = ws + g32;
        scan_seg<32><<<dim3(NBH * 32), dim3(128), 0, stream>>>(k, v, a, b, gk, G, MA, MA, 32);
        combine<32><<<dim3(NBH * 4), dim3(256), 0, stream>>>(MA, MA, 32, G);
        scan_out<32><<<dim3(NBH * 32), dim3(64), 0, stream>>>(q, k, v, a, b, gk, G, out);
    } else if (ws_size >= need32b) {
        // NP=32; G in ws, M slots p<16 in d_out, p>=16 in ws tail
        float* G  = ws;
        float* MA = out;
        float* MB = ws + g32;
        scan_seg<32><<<dim3(NBH * 32), dim3(128), 0, stream>>>(k, v, a, b, gk, G, MA, MB, 16);
        combine<32><<<dim3(NBH * 4), dim3(256), 0, stream>>>(MA, MB, 16, G);
        scan_out<32><<<dim3(NBH * 32), dim3(64), 0, stream>>>(q, k, v, a, b, gk, G, out);
    } else {
        // NP=16 (round-2 proven memory plan): G in ws (16 MiB), M in d_out
        float* G  = ws;
        float* MA = out;
        scan_seg<64><<<dim3(NBH * 16), dim3(128), 0, stream>>>(k, v, a, b, gk, G, MA, MA, 16);
        combine<16><<<dim3(NBH * 4), dim3(256), 0, stream>>>(MA, MA, 16, G);
        scan_out<64><<<dim3(NBH * 16), dim3(64), 0, stream>>>(q, k, v, a, b, gk, G, out);
    }

    epilogue<<<dim3(Bb * Ss * Hh / 4), dim3(256), 0, stream>>>(
        q, k, v, r_k, g, gns, gnb, out);
}

// Round 5
// 327.830 us; speedup vs baseline: 4.2168x; 1.3538x over previous
//
#include <hip/hip_runtime.h>
#include <hip/hip_bf16.h>

constexpr int Bb = 2, Hh = 32, Ss = 1024, Dd = 64;
constexpr int NBH = Bb * Hh;     // 64

// M-slot indirection: slots p < nplo live in bufA, the rest in bufB.
__device__ __forceinline__ float* m_slot(float* A, float* B, int nplo,
                                         int bh, int p, int np) {
    return (p < nplo) ? A + ((size_t)bh * nplo + p) * 4096
                      : B + ((size_t)bh * (np - nplo) + (p - nplo)) * 4096;
}

// ---------------------------------------------------------------------------
// Phase 1: per (bh,p) segment compute G_p (blockIdx.y==0: zero-init scan with
// k v^T input) or M_p (blockIdx.y==1: identity-init, no input).
// 256 thr = 4 waves (wave64!); wave w owns k-rows [16w,16w+16) -> h[16].
// a^T h via parity-double-buffered LDS partials, ONE barrier per step.
// All per-row scalars are LDS broadcasts from CH-step staging.
// ---------------------------------------------------------------------------
template<int SEG, int CH>
__global__ __launch_bounds__(256, 6) void scan_seg(
    const float* __restrict__ kp, const float* __restrict__ vp,
    const float* __restrict__ ap, const float* __restrict__ bp,
    const float* __restrict__ gkp,
    float* __restrict__ Gbuf, float* MbufA, float* MbufB, int nplo)
{
    constexpr int NP = Ss / SEG;
    const int tid  = (int)threadIdx.x;
    const int lane = tid & 63;
    const int w    = __builtin_amdgcn_readfirstlane(tid >> 6);   // 0..3
    const int r0   = w << 4;
    const int mode = (int)blockIdx.y;            // 0 = G, 1 = M
    const int bid  = (int)blockIdx.x;            // bh*NP + p
    const size_t segbase = (size_t)bid * (SEG * Dd);

    __shared__ float la[CH * 64], lb[CH * 64], lw_[CH * 64];
    __shared__ float lk[CH * 64], lv[CH * 64];
    __shared__ float red[2][4][64];

    float h[16];
#pragma unroll
    for (int r = 0; r < 16; ++r) h[r] = mode ? ((r0 + r == lane) ? 1.f : 0.f) : 0.f;

    for (int c0 = 0; c0 < SEG; c0 += CH) {
        __syncthreads();                          // prior chunk reads done
        {
            const size_t gb = segbase + (size_t)c0 * 64;
            const float4* a4 = (const float4*)(ap + gb);
            const float4* b4 = (const float4*)(bp + gb);
            const float4* g4 = (const float4*)(gkp + gb);
            const float4* k4 = (const float4*)(kp + gb);
            const float4* v4 = (const float4*)(vp + gb);
#pragma unroll
            for (int i = tid; i < CH * 16; i += 256) {
                ((float4*)la)[i] = a4[i];
                ((float4*)lb)[i] = b4[i];
                float4 g = g4[i], e;
                e.x = __expf(g.x); e.y = __expf(g.y);
                e.z = __expf(g.z); e.w = __expf(g.w);
                ((float4*)lw_)[i] = e;
                if (mode == 0) {
                    ((float4*)lk)[i] = k4[i];
                    ((float4*)lv)[i] = v4[i];
                }
            }
        }
        __syncthreads();                          // staging visible

        for (int tl = 0; tl < CH; ++tl) {
            const int t = c0 + tl;
            // ---- partial a^T h over my 16 rows
            const float4* ar = (const float4*)(la + tl * 64 + r0);
            float s0 = 0.f, s1 = 0.f, s2 = 0.f, s3 = 0.f;
#pragma unroll
            for (int jj = 0; jj < 4; ++jj) {
                const float4 a4 = ar[jj];
                s0 = fmaf(a4.x, h[4*jj+0], s0);
                s1 = fmaf(a4.y, h[4*jj+1], s1);
                s2 = fmaf(a4.z, h[4*jj+2], s2);
                s3 = fmaf(a4.w, h[4*jj+3], s3);
            }
            red[t & 1][w][lane] = (s0 + s1) + (s2 + s3);
            __syncthreads();                      // the ONLY per-step barrier
            const float ah = (red[t & 1][0][lane] + red[t & 1][1][lane]) +
                             (red[t & 1][2][lane] + red[t & 1][3][lane]);

            const float4* br = (const float4*)(lb  + tl * 64 + r0);
            const float4* wr = (const float4*)(lw_ + tl * 64 + r0);
            if (mode == 0) {
                const float u = lv[tl * 64 + lane];
                const float4* kr = (const float4*)(lk + tl * 64 + r0);
#pragma unroll
                for (int jj = 0; jj < 4; ++jj) {
                    const float4 b4 = br[jj], k4 = kr[jj], w4 = wr[jj];
                    h[4*jj+0] = fmaf(w4.x, h[4*jj+0], fmaf(b4.x, ah, k4.x * u));
                    h[4*jj+1] = fmaf(w4.y, h[4*jj+1], fmaf(b4.y, ah, k4.y * u));
                    h[4*jj+2] = fmaf(w4.z, h[4*jj+2], fmaf(b4.z, ah, k4.z * u));
                    h[4*jj+3] = fmaf(w4.w, h[4*jj+3], fmaf(b4.w, ah, k4.w * u));
                }
            } else {
#pragma unroll
                for (int jj = 0; jj < 4; ++jj) {
                    const float4 b4 = br[jj], w4 = wr[jj];
                    h[4*jj+0] = fmaf(w4.x, h[4*jj+0], b4.x * ah);
                    h[4*jj+1] = fmaf(w4.y, h[4*jj+1], b4.y * ah);
                    h[4*jj+2] = fmaf(w4.z, h[4*jj+2], b4.z * ah);
                    h[4*jj+3] = fmaf(w4.w, h[4*jj+3], b4.w * ah);
                }
            }
        }
    }

    const int p  = bid & (NP - 1);
    const int bh = bid / NP;
    float* dst = (mode == 0) ? Gbuf + (size_t)bid * 4096
                             : m_slot(MbufA, MbufB, nplo, bh, p, NP);
#pragma unroll
    for (int r = 0; r < 16; ++r) dst[(r0 + r) * 64 + lane] = h[r];
}

// ---------------------------------------------------------------------------
// Phase 2 (unchanged, proven): SW_p = M_p * SW_{p-1} + G_p, 4 col-blocks/bh.
// ---------------------------------------------------------------------------
template<int NP>
__global__ __launch_bounds__(256) void combine(
    const float* MbufA, const float* MbufB, int nplo, float* __restrict__ Gbuf)
{
    const int bh  = (int)blockIdx.x >> 2;
    const int cb  = (int)blockIdx.x & 3;
    const int c0  = cb * 16;
    const int tid = (int)threadIdx.x;
    const int cl  = tid & 15;
    const int c   = c0 + cl;
    const int r0  = (tid >> 4) * 4;

    __shared__ float SW[64][16];
    for (int i = tid; i < 1024; i += 256)
        SW[i >> 4][i & 15] = Gbuf[(size_t)bh * NP * 4096 + (i >> 4) * 64 + c0 + (i & 15)];
    __syncthreads();

    for (int p = 1; p < NP; ++p) {
        const float* Mp = m_slot((float*)MbufA, (float*)MbufB, nplo, bh, p, NP);
        float* Gp = Gbuf + ((size_t)bh * NP + p) * 4096;

        float acc[4];
#pragma unroll
        for (int r = 0; r < 4; ++r) acc[r] = Gp[(r0 + r) * 64 + c];

#pragma unroll
        for (int r = 0; r < 4; ++r) {
            const float4* mr = (const float4*)(Mp + (r0 + r) * 64);
            float s0 = 0.f, s1 = 0.f, s2 = 0.f, s3 = 0.f;
#pragma unroll
            for (int m4 = 0; m4 < 16; ++m4) {
                const float4 m = mr[m4];
                s0 = fmaf(m.x, SW[4*m4+0][cl], s0);
                s1 = fmaf(m.y, SW[4*m4+1][cl], s1);
                s2 = fmaf(m.z, SW[4*m4+2][cl], s2);
                s3 = fmaf(m.w, SW[4*m4+3][cl], s3);
            }
            acc[r] += (s0 + s1) + (s2 + s3);
        }
#pragma unroll
        for (int r = 0; r < 4; ++r) Gp[(r0 + r) * 64 + c] = acc[r];
        __syncthreads();
#pragma unroll
        for (int r = 0; r < 4; ++r) SW[r0 + r][cl] = acc[r];
        __syncthreads();
    }
}

// ---------------------------------------------------------------------------
// Phase 3: replay segment p from SW_{p-1}; o_t = h_t^T q_t -> d_out [B,S,hid].
// 256 thr = 4 waves (wave64), 16 rows each. Same single-barrier scheme; the
// o-reduction is deferred one step so it reuses the same barrier.
// ---------------------------------------------------------------------------
template<int SEG, int CH>
__global__ __launch_bounds__(256, 6) void scan_out(
    const float* __restrict__ qp, const float* __restrict__ kp,
    const float* __restrict__ vp, const float* __restrict__ ap,
    const float* __restrict__ bp, const float* __restrict__ gkp,
    const float* __restrict__ Gbuf, float* __restrict__ out)
{
    constexpr int NP = Ss / SEG;
    const int tid  = (int)threadIdx.x;
    const int lane = tid & 63;
    const int w    = __builtin_amdgcn_readfirstlane(tid >> 6);   // 0..3
    const int r0   = w << 4;
    const int bid  = (int)blockIdx.x;            // bh*NP + p
    const int p    = bid & (NP - 1);
    const int bh   = bid / NP;
    const int b    = bh >> 5, hh = bh & (Hh - 1);
    const size_t segbase = (size_t)bid * (SEG * Dd);

    __shared__ float la[CH * 64], lb[CH * 64], lw_[CH * 64];
    __shared__ float lk[CH * 64], lv[CH * 64], lq[CH * 64];
    __shared__ float red_a[2][4][64];
    __shared__ float red_o[2][4][64];

    float h[16];
    if (p) {
        const float* sw = Gbuf + (size_t)(bid - 1) * 4096;
#pragma unroll
        for (int r = 0; r < 16; ++r) h[r] = sw[(r0 + r) * 64 + lane];
    } else {
#pragma unroll
        for (int r = 0; r < 16; ++r) h[r] = 0.f;
    }

    for (int c0 = 0; c0 < SEG; c0 += CH) {
        __syncthreads();
        {
            const size_t gb = segbase + (size_t)c0 * 64;
            const float4* a4 = (const float4*)(ap + gb);
            const float4* b4 = (const float4*)(bp + gb);
            const float4* g4 = (const float4*)(gkp + gb);
            const float4* k4 = (const float4*)(kp + gb);
            const float4* v4 = (const float4*)(vp + gb);
            const float4* q4 = (const float4*)(qp + gb);
            for (int i = tid; i < CH * 16; i += 256) {
                ((float4*)la)[i] = a4[i];
                ((float4*)lb)[i] = b4[i];
                float4 g = g4[i], e;
                e.x = __expf(g.x); e.y = __expf(g.y);
                e.z = __expf(g.z); e.w = __expf(g.w);
                ((float4*)lw_)[i] = e;
                ((float4*)lk)[i] = k4[i];
                ((float4*)lv)[i] = v4[i];
                ((float4*)lq)[i] = q4[i];
            }
        }
        __syncthreads();

        for (int tl = 0; tl < CH; ++tl) {
            const int t = c0 + tl;
            const float4* ar = (const float4*)(la + tl * 64 + r0);
            float s0 = 0.f, s1 = 0.f, s2 = 0.f, s3 = 0.f;
#pragma unroll
            for (int jj = 0; jj < 4; ++jj) {
                const float4 a4 = ar[jj];
                s0 = fmaf(a4.x, h[4*jj+0], s0);
                s1 = fmaf(a4.y, h[4*jj+1], s1);
                s2 = fmaf(a4.z, h[4*jj+2], s2);
                s3 = fmaf(a4.w, h[4*jj+3], s3);
            }
            red_a[t & 1][w][lane] = (s0 + s1) + (s2 + s3);
            __syncthreads();                      // the ONLY per-step barrier
            const float ah = (red_a[t & 1][0][lane] + red_a[t & 1][1][lane]) +
                             (red_a[t & 1][2][lane] + red_a[t & 1][3][lane]);

            if (w == 0 && t > 0) {                // deferred o_{t-1} store
                const int pe = (t - 1) & 1;
                const float os = (red_o[pe][0][lane] + red_o[pe][1][lane]) +
                                 (red_o[pe][2][lane] + red_o[pe][3][lane]);
                const int s = p * SEG + t - 1;
                out[(((size_t)b * Ss + s) * Hh + hh) * Dd + lane] = os;
            }

            const float u = lv[tl * 64 + lane];
            const float4* br = (const float4*)(lb  + tl * 64 + r0);
            const float4* kr = (const float4*)(lk  + tl * 64 + r0);
            const float4* wr = (const float4*)(lw_ + tl * 64 + r0);
            const float4* qr = (const float4*)(lq  + tl * 64 + r0);
            float o0 = 0.f, o1 = 0.f, o2 = 0.f, o3 = 0.f;
#pragma unroll
            for (int jj = 0; jj < 4; ++jj) {
                const float4 b4 = br[jj], k4 = kr[jj], w4 = wr[jj], q4 = qr[jj];
                h[4*jj+0] = fmaf(w4.x, h[4*jj+0], fmaf(b4.x, ah, k4.x * u));
                o0 = fmaf(q4.x, h[4*jj+0], o0);
                h[4*jj+1] = fmaf(w4.y, h[4*jj+1], fmaf(b4.y, ah, k4.y * u));
                o1 = fmaf(q4.y, h[4*jj+1], o1);
                h[4*jj+2] = fmaf(w4.z, h[4*jj+2], fmaf(b4.z, ah, k4.z * u));
                o2 = fmaf(q4.z, h[4*jj+2], o2);
                h[4*jj+3] = fmaf(w4.w, h[4*jj+3], fmaf(b4.w, ah, k4.w * u));
                o3 = fmaf(q4.w, h[4*jj+3], o3);
            }
            red_o[t & 1][w][lane] = (o0 + o1) + (o2 + o3);
        }
    }

    __syncthreads();
    if (w == 0) {                                // tail: o_{SEG-1}
        const int pe = (SEG - 1) & 1;
        const float os = (red_o[pe][0][lane] + red_o[pe][1][lane]) +
                         (red_o[pe][2][lane] + red_o[pe][3][lane]);
        const int s = p * SEG + SEG - 1;
        out[(((size_t)b * Ss + s) * Hh + hh) * Dd + lane] = os;
    }
}

// ---------------------------------------------------------------------------
// Epilogue (unchanged): in-place GroupNorm + correction + gate on d_out.
// ---------------------------------------------------------------------------
__global__ __launch_bounds__(256) void epilogue(
    const float* __restrict__ qp, const float* __restrict__ kp,
    const float* __restrict__ vp, const float* __restrict__ rk,
    const float* __restrict__ gp, const float* __restrict__ sc,
    const float* __restrict__ bi, float* __restrict__ out)
{
    const int lane = (int)(threadIdx.x & 63u);
    const int gid  = (int)blockIdx.x * 4 + (int)(threadIdx.x >> 6);
    const int hh   = gid & (Hh - 1);
    const int bs   = gid >> 5;
    const int b    = bs >> 10;
    const int s    = bs & (Ss - 1);

    const size_t ioff = ((size_t)(b * Hh + hh) * Ss + s) * Dd + lane;
    const float qv = qp[ioff];
    const float kv = kp[ioff];
    const float vv = vp[ioff];
    const float r  = rk[hh * Dd + lane];

    const size_t goff = (size_t)bs * (Hh * Dd) + hh * Dd + lane;
    const float o = out[goff];

    float s1 = o, s2 = o * o, s3 = qv * kv * r;
#pragma unroll
    for (int m = 32; m >= 1; m >>= 1) {
        s1 += __shfl_xor(s1, m, 64);
        s2 += __shfl_xor(s2, m, 64);
        s3 += __shfl_xor(s3, m, 64);
    }
    const float mu  = s1 * (1.f / 64.f);
    const float var = fmaf(-mu, mu, s2 * (1.f / 64.f));
    const float on  = (o - mu) * rsqrtf(var + 1e-5f);

    out[goff] = (fmaf(on, sc[hh * Dd + lane], bi[hh * Dd + lane]) + s3 * vv) * gp[goff];
}

// ---------------------------------------------------------------------------
extern "C" void kernel_launch(void* const* d_in, const int* in_sizes, int n_in,
                              void* d_out, int out_size, void* d_ws, size_t ws_size,
                              hipStream_t stream)
{
    const float* q   = (const float*)d_in[0];
    const float* k   = (const float*)d_in[1];
    const float* v   = (const float*)d_in[2];
    const float* a   = (const float*)d_in[3];
    const float* b   = (const float*)d_in[4];
    const float* gk  = (const float*)d_in[5];
    const float* r_k = (const float*)d_in[6];
    const float* g   = (const float*)d_in[7];
    const float* gns = (const float*)d_in[8];
    const float* gnb = (const float*)d_in[9];
    float* out = (float*)d_out;
    float* ws  = (float*)d_ws;

    const size_t slotf   = 4096;
    const size_t g32     = (size_t)NBH * 32 * slotf;
    const size_t need32  = g32 * 4 * 2;                              // 64 MiB
    const size_t need32b = g32 * 4 + (size_t)NBH * 16 * slotf * 4;   // 48 MiB

    if (ws_size >= need32) {
        float* G  = ws;
        float* MA = ws + g32;
        scan_seg<32,16><<<dim3(NBH * 32, 2), dim3(256), 0, stream>>>(k, v, a, b, gk, G, MA, MA, 32);
        combine<32><<<dim3(NBH * 4), dim3(256), 0, stream>>>(MA, MA, 32, G);
        scan_out<32,8><<<dim3(NBH * 32), dim3(256), 0, stream>>>(q, k, v, a, b, gk, G, out);
    } else if (ws_size >= need32b) {
        float* G  = ws;
        float* MA = out;
        float* MB = ws + g32;
        scan_seg<32,16><<<dim3(NBH * 32, 2), dim3(256), 0, stream>>>(k, v, a, b, gk, G, MA, MB, 16);
        combine<32><<<dim3(NBH * 4), dim3(256), 0, stream>>>(MA, MB, 16, G);
        scan_out<32,8><<<dim3(NBH * 32), dim3(256), 0, stream>>>(q, k, v, a, b, gk, G, out);
    } else {
        float* G  = ws;
        float* MA = out;
        scan_seg<64,16><<<dim3(NBH * 16, 2), dim3(256), 0, stream>>>(k, v, a, b, gk, G, MA, MA, 16);
        combine<16><<<dim3(NBH * 4), dim3(256), 0, stream>>>(MA, MA, 16, G);
        scan_out<64,8><<<dim3(NBH * 16), dim3(256), 0, stream>>>(q, k, v, a, b, gk, G, out);
    }

    epilogue<<<dim3(Bb * Ss * Hh / 4), dim3(256), 0, stream>>>(
        q, k, v, r_k, g, gns, gnb, out);
}

// Round 6
// 242.640 us; speedup vs baseline: 5.6973x; 1.3511x over previous
//
#include <hip/hip_runtime.h>
#include <hip/hip_bf16.h>

constexpr int Bb = 2, Hh = 32, Ss = 1024, Dd = 64;
constexpr int NBH = Bb * Hh;     // 64

// M-slot indirection: slots p < nplo live in bufA, the rest in bufB.
__device__ __forceinline__ float* m_slot(float* A, float* B, int nplo,
                                         int bh, int p, int np) {
    return (p < nplo) ? A + ((size_t)bh * nplo + p) * 4096
                      : B + ((size_t)bh * (np - nplo) + (p - nplo)) * 4096;
}

// ---------------------------------------------------------------------------
// Phase 1 (unchanged, proven): per (bh,p) segment compute G_p (blockIdx.y==0)
// or M_p (blockIdx.y==1). 256 thr = 4 waves; wave w owns k-rows [16w,16w+16).
// ---------------------------------------------------------------------------
template<int SEG, int CH>
__global__ __launch_bounds__(256, 6) void scan_seg(
    const float* __restrict__ kp, const float* __restrict__ vp,
    const float* __restrict__ ap, const float* __restrict__ bp,
    const float* __restrict__ gkp,
    float* __restrict__ Gbuf, float* MbufA, float* MbufB, int nplo)
{
    constexpr int NP = Ss / SEG;
    const int tid  = (int)threadIdx.x;
    const int lane = tid & 63;
    const int w    = __builtin_amdgcn_readfirstlane(tid >> 6);   // 0..3
    const int r0   = w << 4;
    const int mode = (int)blockIdx.y;            // 0 = G, 1 = M
    const int bid  = (int)blockIdx.x;            // bh*NP + p
    const size_t segbase = (size_t)bid * (SEG * Dd);

    __shared__ float la[CH * 64], lb[CH * 64], lw_[CH * 64];
    __shared__ float lk[CH * 64], lv[CH * 64];
    __shared__ float red[2][4][64];

    float h[16];
#pragma unroll
    for (int r = 0; r < 16; ++r) h[r] = mode ? ((r0 + r == lane) ? 1.f : 0.f) : 0.f;

    for (int c0 = 0; c0 < SEG; c0 += CH) {
        __syncthreads();                          // prior chunk reads done
        {
            const size_t gb = segbase + (size_t)c0 * 64;
            const float4* a4 = (const float4*)(ap + gb);
            const float4* b4 = (const float4*)(bp + gb);
            const float4* g4 = (const float4*)(gkp + gb);
            const float4* k4 = (const float4*)(kp + gb);
            const float4* v4 = (const float4*)(vp + gb);
#pragma unroll
            for (int i = tid; i < CH * 16; i += 256) {
                ((float4*)la)[i] = a4[i];
                ((float4*)lb)[i] = b4[i];
                float4 g = g4[i], e;
                e.x = __expf(g.x); e.y = __expf(g.y);
                e.z = __expf(g.z); e.w = __expf(g.w);
                ((float4*)lw_)[i] = e;
                if (mode == 0) {
                    ((float4*)lk)[i] = k4[i];
                    ((float4*)lv)[i] = v4[i];
                }
            }
        }
        __syncthreads();                          // staging visible

        for (int tl = 0; tl < CH; ++tl) {
            const int t = c0 + tl;
            const float4* ar = (const float4*)(la + tl * 64 + r0);
            float s0 = 0.f, s1 = 0.f, s2 = 0.f, s3 = 0.f;
#pragma unroll
            for (int jj = 0; jj < 4; ++jj) {
                const float4 a4 = ar[jj];
                s0 = fmaf(a4.x, h[4*jj+0], s0);
                s1 = fmaf(a4.y, h[4*jj+1], s1);
                s2 = fmaf(a4.z, h[4*jj+2], s2);
                s3 = fmaf(a4.w, h[4*jj+3], s3);
            }
            red[t & 1][w][lane] = (s0 + s1) + (s2 + s3);
            __syncthreads();                      // the ONLY per-step barrier
            const float ah = (red[t & 1][0][lane] + red[t & 1][1][lane]) +
                             (red[t & 1][2][lane] + red[t & 1][3][lane]);

            const float4* br = (const float4*)(lb  + tl * 64 + r0);
            const float4* wr = (const float4*)(lw_ + tl * 64 + r0);
            if (mode == 0) {
                const float u = lv[tl * 64 + lane];
                const float4* kr = (const float4*)(lk + tl * 64 + r0);
#pragma unroll
                for (int jj = 0; jj < 4; ++jj) {
                    const float4 b4 = br[jj], k4 = kr[jj], w4 = wr[jj];
                    h[4*jj+0] = fmaf(w4.x, h[4*jj+0], fmaf(b4.x, ah, k4.x * u));
                    h[4*jj+1] = fmaf(w4.y, h[4*jj+1], fmaf(b4.y, ah, k4.y * u));
                    h[4*jj+2] = fmaf(w4.z, h[4*jj+2], fmaf(b4.z, ah, k4.z * u));
                    h[4*jj+3] = fmaf(w4.w, h[4*jj+3], fmaf(b4.w, ah, k4.w * u));
                }
            } else {
#pragma unroll
                for (int jj = 0; jj < 4; ++jj) {
                    const float4 b4 = br[jj], w4 = wr[jj];
                    h[4*jj+0] = fmaf(w4.x, h[4*jj+0], b4.x * ah);
                    h[4*jj+1] = fmaf(w4.y, h[4*jj+1], b4.y * ah);
                    h[4*jj+2] = fmaf(w4.z, h[4*jj+2], b4.z * ah);
                    h[4*jj+3] = fmaf(w4.w, h[4*jj+3], b4.w * ah);
                }
            }
        }
    }

    const int p  = bid & (NP - 1);
    const int bh = bid / NP;
    float* dst = (mode == 0) ? Gbuf + (size_t)bid * 4096
                             : m_slot(MbufA, MbufB, nplo, bh, p, NP);
#pragma unroll
    for (int r = 0; r < 16; ++r) dst[(r0 + r) * 64 + lane] = h[r];
}

// ---------------------------------------------------------------------------
// Phase 2 REWRITTEN: SW_p = M_p * SW_{p-1} + G_p, 4 col-blocks/bh.
// Double-buffered reg-staged M (issue loads for M_{p+2} during p's compute,
// ds_write after the barrier). M stored swizzled (slot f ^ ((f>>4)&4)) so the
// 4 simultaneous row reads are 2-way (free). State col-major swT[16][68].
// Thread: cl = tid&15 (local col), rg = tid>>4 (rows 4rg..4rg+3).
// ---------------------------------------------------------------------------
template<int NP>
__global__ __launch_bounds__(256) void combine(
    const float* MbufA, const float* MbufB, int nplo, float* __restrict__ Gbuf)
{
    const int bh  = (int)blockIdx.x >> 2;
    const int cb  = (int)blockIdx.x & 3;
    const int c0  = cb * 16;
    const int tid = (int)threadIdx.x;
    const int cl  = tid & 15;
    const int c   = c0 + cl;
    const int rg  = tid >> 4;            // 0..15
    const int r0  = rg * 4;
    const int xorv = (rg & 1) << 2;      // row&4 for rows 4rg..4rg+3

    __shared__ float4 Ml[2][1024];       // 32 KiB, swizzled M double buffer
    __shared__ __align__(16) float swT[16][68];   // state, col-major, padded

    // ---- init: SW0 = G[p=0] column slice
    {
        const float* G0 = Gbuf + (size_t)bh * NP * 4096;
        for (int i = tid; i < 1024; i += 256)
            swT[i & 15][i >> 4] = G0[(i >> 4) * 64 + c0 + (i & 15)];
    }

    // ---- prologue: stage M[1] -> regs -> Ml[0]; issue M[2] -> regs
    float4 mreg[4];
    if (NP > 1) {
        const float4* Mp = (const float4*)m_slot((float*)MbufA, (float*)MbufB,
                                                 nplo, bh, 1, NP);
#pragma unroll
        for (int j = 0; j < 4; ++j) mreg[j] = Mp[j * 256 + tid];
    }
    __syncthreads();                     // swT init visible before any reads
#pragma unroll
    for (int j = 0; j < 4; ++j) {
        const int f = j * 256 + tid;
        Ml[0][f ^ ((f >> 4) & 4)] = mreg[j];
    }
    if (NP > 2) {
        const float4* Mp = (const float4*)m_slot((float*)MbufA, (float*)MbufB,
                                                 nplo, bh, 2, NP);
#pragma unroll
        for (int j = 0; j < 4; ++j) mreg[j] = Mp[j * 256 + tid];
    }
    __syncthreads();                     // Ml[0] visible

    for (int p = 1; p < NP; ++p) {
        const int par = (p - 1) & 1;
        float* Gp = Gbuf + ((size_t)bh * NP + p) * 4096;

        // prefetch G_p slice (used after compute)
        float gacc[4];
#pragma unroll
        for (int r = 0; r < 4; ++r) gacc[r] = Gp[(r0 + r) * 64 + c];

        // ---- compute acc = M_p[rows r0..r0+3] . SW_{p-1}[:, c]
        float accA[4] = {0.f, 0.f, 0.f, 0.f};
        float accB[4] = {0.f, 0.f, 0.f, 0.f};
        const float4* swr = (const float4*)&swT[cl][0];
#pragma unroll
        for (int m4 = 0; m4 < 16; ++m4) {
            const float4 s = swr[m4];
            const int ms = m4 ^ xorv;
#pragma unroll
            for (int r = 0; r < 4; ++r) {
                const float4 m = Ml[par][(r0 + r) * 16 + ms];
                accA[r] = fmaf(m.x, s.x, fmaf(m.y, s.y, accA[r]));
                accB[r] = fmaf(m.z, s.z, fmaf(m.w, s.w, accB[r]));
            }
        }
        __syncthreads();                 // swT / Ml[par] reads done

        // ---- write new state (LDS + global) and rotate M buffers
#pragma unroll
        for (int r = 0; r < 4; ++r) {
            const float val = accA[r] + accB[r] + gacc[r];
            swT[cl][r0 + r] = val;
            Gp[(r0 + r) * 64 + c] = val;
        }
        if (p + 1 < NP) {
#pragma unroll
            for (int j = 0; j < 4; ++j) {
                const int f = j * 256 + tid;
                Ml[par ^ 1][f ^ ((f >> 4) & 4)] = mreg[j];
            }
        }
        if (p + 2 < NP) {
            const float4* Mp = (const float4*)m_slot((float*)MbufA, (float*)MbufB,
                                                     nplo, bh, p + 2, NP);
#pragma unroll
            for (int j = 0; j < 4; ++j) mreg[j] = Mp[j * 256 + tid];
        }
        __syncthreads();                 // swT + Ml[par^1] visible
    }
}

// ---------------------------------------------------------------------------
// Phase 3 (unchanged, proven): replay segment p from SW_{p-1};
// o_t = h_t^T q_t -> d_out [B,S,hid]. 256 thr = 4 waves, 16 rows each.
// ---------------------------------------------------------------------------
template<int SEG, int CH>
__global__ __launch_bounds__(256, 6) void scan_out(
    const float* __restrict__ qp, const float* __restrict__ kp,
    const float* __restrict__ vp, const float* __restrict__ ap,
    const float* __restrict__ bp, const float* __restrict__ gkp,
    const float* __restrict__ Gbuf, float* __restrict__ out)
{
    constexpr int NP = Ss / SEG;
    const int tid  = (int)threadIdx.x;
    const int lane = tid & 63;
    const int w    = __builtin_amdgcn_readfirstlane(tid >> 6);   // 0..3
    const int r0   = w << 4;
    const int bid  = (int)blockIdx.x;            // bh*NP + p
    const int p    = bid & (NP - 1);
    const int bh   = bid / NP;
    const int b    = bh >> 5, hh = bh & (Hh - 1);
    const size_t segbase = (size_t)bid * (SEG * Dd);

    __shared__ float la[CH * 64], lb[CH * 64], lw_[CH * 64];
    __shared__ float lk[CH * 64], lv[CH * 64], lq[CH * 64];
    __shared__ float red_a[2][4][64];
    __shared__ float red_o[2][4][64];

    float h[16];
    if (p) {
        const float* sw = Gbuf + (size_t)(bid - 1) * 4096;
#pragma unroll
        for (int r = 0; r < 16; ++r) h[r] = sw[(r0 + r) * 64 + lane];
    } else {
#pragma unroll
        for (int r = 0; r < 16; ++r) h[r] = 0.f;
    }

    for (int c0 = 0; c0 < SEG; c0 += CH) {
        __syncthreads();
        {
            const size_t gb = segbase + (size_t)c0 * 64;
            const float4* a4 = (const float4*)(ap + gb);
            const float4* b4 = (const float4*)(bp + gb);
            const float4* g4 = (const float4*)(gkp + gb);
            const float4* k4 = (const float4*)(kp + gb);
            const float4* v4 = (const float4*)(vp + gb);
            const float4* q4 = (const float4*)(qp + gb);
            for (int i = tid; i < CH * 16; i += 256) {
                ((float4*)la)[i] = a4[i];
                ((float4*)lb)[i] = b4[i];
                float4 g = g4[i], e;
                e.x = __expf(g.x); e.y = __expf(g.y);
                e.z = __expf(g.z); e.w = __expf(g.w);
                ((float4*)lw_)[i] = e;
                ((float4*)lk)[i] = k4[i];
                ((float4*)lv)[i] = v4[i];
                ((float4*)lq)[i] = q4[i];
            }
        }
        __syncthreads();

        for (int tl = 0; tl < CH; ++tl) {
            const int t = c0 + tl;
            const float4* ar = (const float4*)(la + tl * 64 + r0);
            float s0 = 0.f, s1 = 0.f, s2 = 0.f, s3 = 0.f;
#pragma unroll
            for (int jj = 0; jj < 4; ++jj) {
                const float4 a4 = ar[jj];
                s0 = fmaf(a4.x, h[4*jj+0], s0);
                s1 = fmaf(a4.y, h[4*jj+1], s1);
                s2 = fmaf(a4.z, h[4*jj+2], s2);
                s3 = fmaf(a4.w, h[4*jj+3], s3);
            }
            red_a[t & 1][w][lane] = (s0 + s1) + (s2 + s3);
            __syncthreads();                      // the ONLY per-step barrier
            const float ah = (red_a[t & 1][0][lane] + red_a[t & 1][1][lane]) +
                             (red_a[t & 1][2][lane] + red_a[t & 1][3][lane]);

            if (w == 0 && t > 0) {                // deferred o_{t-1} store
                const int pe = (t - 1) & 1;
                const float os = (red_o[pe][0][lane] + red_o[pe][1][lane]) +
                                 (red_o[pe][2][lane] + red_o[pe][3][lane]);
                const int s = p * SEG + t - 1;
                out[(((size_t)b * Ss + s) * Hh + hh) * Dd + lane] = os;
            }

            const float u = lv[tl * 64 + lane];
            const float4* br = (const float4*)(lb  + tl * 64 + r0);
            const float4* kr = (const float4*)(lk  + tl * 64 + r0);
            const float4* wr = (const float4*)(lw_ + tl * 64 + r0);
            const float4* qr = (const float4*)(lq  + tl * 64 + r0);
            float o0 = 0.f, o1 = 0.f, o2 = 0.f, o3 = 0.f;
#pragma unroll
            for (int jj = 0; jj < 4; ++jj) {
                const float4 b4 = br[jj], k4 = kr[jj], w4 = wr[jj], q4 = qr[jj];
                h[4*jj+0] = fmaf(w4.x, h[4*jj+0], fmaf(b4.x, ah, k4.x * u));
                o0 = fmaf(q4.x, h[4*jj+0], o0);
                h[4*jj+1] = fmaf(w4.y, h[4*jj+1], fmaf(b4.y, ah, k4.y * u));
                o1 = fmaf(q4.y, h[4*jj+1], o1);
                h[4*jj+2] = fmaf(w4.z, h[4*jj+2], fmaf(b4.z, ah, k4.z * u));
                o2 = fmaf(q4.z, h[4*jj+2], o2);
                h[4*jj+3] = fmaf(w4.w, h[4*jj+3], fmaf(b4.w, ah, k4.w * u));
                o3 = fmaf(q4.w, h[4*jj+3], o3);
            }
            red_o[t & 1][w][lane] = (o0 + o1) + (o2 + o3);
        }
    }

    __syncthreads();
    if (w == 0) {                                // tail: o_{SEG-1}
        const int pe = (SEG - 1) & 1;
        const float os = (red_o[pe][0][lane] + red_o[pe][1][lane]) +
                         (red_o[pe][2][lane] + red_o[pe][3][lane]);
        const int s = p * SEG + SEG - 1;
        out[(((size_t)b * Ss + s) * Hh + hh) * Dd + lane] = os;
    }
}

// ---------------------------------------------------------------------------
// Epilogue (unchanged): in-place GroupNorm + correction + gate on d_out.
// ---------------------------------------------------------------------------
__global__ __launch_bounds__(256) void epilogue(
    const float* __restrict__ qp, const float* __restrict__ kp,
    const float* __restrict__ vp, const float* __restrict__ rk,
    const float* __restrict__ gp, const float* __restrict__ sc,
    const float* __restrict__ bi, float* __restrict__ out)
{
    const int lane = (int)(threadIdx.x & 63u);
    const int gid  = (int)blockIdx.x * 4 + (int)(threadIdx.x >> 6);
    const int hh   = gid & (Hh - 1);
    const int bs   = gid >> 5;
    const int b    = bs >> 10;
    const int s    = bs & (Ss - 1);

    const size_t ioff = ((size_t)(b * Hh + hh) * Ss + s) * Dd + lane;
    const float qv = qp[ioff];
    const float kv = kp[ioff];
    const float vv = vp[ioff];
    const float r  = rk[hh * Dd + lane];

    const size_t goff = (size_t)bs * (Hh * Dd) + hh * Dd + lane;
    const float o = out[goff];

    float s1 = o, s2 = o * o, s3 = qv * kv * r;
#pragma unroll
    for (int m = 32; m >= 1; m >>= 1) {
        s1 += __shfl_xor(s1, m, 64);
        s2 += __shfl_xor(s2, m, 64);
        s3 += __shfl_xor(s3, m, 64);
    }
    const float mu  = s1 * (1.f / 64.f);
    const float var = fmaf(-mu, mu, s2 * (1.f / 64.f));
    const float on  = (o - mu) * rsqrtf(var + 1e-5f);

    out[goff] = (fmaf(on, sc[hh * Dd + lane], bi[hh * Dd + lane]) + s3 * vv) * gp[goff];
}

// ---------------------------------------------------------------------------
extern "C" void kernel_launch(void* const* d_in, const int* in_sizes, int n_in,
                              void* d_out, int out_size, void* d_ws, size_t ws_size,
                              hipStream_t stream)
{
    const float* q   = (const float*)d_in[0];
    const float* k   = (const float*)d_in[1];
    const float* v   = (const float*)d_in[2];
    const float* a   = (const float*)d_in[3];
    const float* b   = (const float*)d_in[4];
    const float* gk  = (const float*)d_in[5];
    const float* r_k = (const float*)d_in[6];
    const float* g   = (const float*)d_in[7];
    const float* gns = (const float*)d_in[8];
    const float* gnb = (const float*)d_in[9];
    float* out = (float*)d_out;
    float* ws  = (float*)d_ws;

    const size_t slotf   = 4096;
    const size_t g32     = (size_t)NBH * 32 * slotf;
    const size_t need32  = g32 * 4 * 2;                              // 64 MiB
    const size_t need32b = g32 * 4 + (size_t)NBH * 16 * slotf * 4;   // 48 MiB

    if (ws_size >= need32) {
        float* G  = ws;
        float* MA = ws + g32;
        scan_seg<32,16><<<dim3(NBH * 32, 2), dim3(256), 0, stream>>>(k, v, a, b, gk, G, MA, MA, 32);
        combine<32><<<dim3(NBH * 4), dim3(256), 0, stream>>>(MA, MA, 32, G);
        scan_out<32,8><<<dim3(NBH * 32), dim3(256), 0, stream>>>(q, k, v, a, b, gk, G, out);
    } else if (ws_size >= need32b) {
        float* G  = ws;
        float* MA = out;
        float* MB = ws + g32;
        scan_seg<32,16><<<dim3(NBH * 32, 2), dim3(256), 0, stream>>>(k, v, a, b, gk, G, MA, MB, 16);
        combine<32><<<dim3(NBH * 4), dim3(256), 0, stream>>>(MA, MB, 16, G);
        scan_out<32,8><<<dim3(NBH * 32), dim3(256), 0, stream>>>(q, k, v, a, b, gk, G, out);
    } else {
        float* G  = ws;
        float* MA = out;
        scan_seg<64,16><<<dim3(NBH * 16, 2), dim3(256), 0, stream>>>(k, v, a, b, gk, G, MA, MA, 16);
        combine<16><<<dim3(NBH * 4), dim3(256), 0, stream>>>(MA, MA, 16, G);
        scan_out<64,8><<<dim3(NBH * 16), dim3(256), 0, stream>>>(q, k, v, a, b, gk, G, out);
    }

    epilogue<<<dim3(Bb * Ss * Hh / 4), dim3(256), 0, stream>>>(
        q, k, v, r_k, g, gns, gnb, out);
}

// Round 7
// 238.284 us; speedup vs baseline: 5.8015x; 1.0183x over previous
//
#include <hip/hip_runtime.h>
#include <hip/hip_bf16.h>

constexpr int Bb = 2, Hh = 32, Ss = 1024, Dd = 64;
constexpr int NBH = Bb * Hh;     // 64

// M-slot indirection: slots p < nplo live in bufA, the rest in bufB.
__device__ __forceinline__ float* m_slot(float* A, float* B, int nplo,
                                         int bh, int p, int np) {
    return (p < nplo) ? A + ((size_t)bh * nplo + p) * 4096
                      : B + ((size_t)bh * (np - nplo) + (p - nplo)) * 4096;
}

// ---------------------------------------------------------------------------
// Phase 1 FUSED: one 512-thread block per (bh,p) segment computes BOTH
//   G_p (waves 0-3: zero-init scan with k v^T input) and
//   M_p (waves 4-7: identity-init homogeneous propagation)
// sharing one LDS staging pass (a,b,exp(gk),k,v) and one parity-double-
// buffered reduction array (ONE barrier per step). Wave w' = wv&3 owns
// k-rows [16w',16w'+16) of its state. Step loop fully unrolled so all LDS
// offsets are compile-time immediates.
// ---------------------------------------------------------------------------
template<int SEG, int CH>
__global__ __launch_bounds__(512, 6) void scan_seg_fused(
    const float* __restrict__ kp, const float* __restrict__ vp,
    const float* __restrict__ ap, const float* __restrict__ bp,
    const float* __restrict__ gkp,
    float* __restrict__ Gbuf, float* MbufA, float* MbufB, int nplo)
{
    constexpr int NP = Ss / SEG;
    const int tid  = (int)threadIdx.x;
    const int lane = tid & 63;
    const int wv   = __builtin_amdgcn_readfirstlane(tid >> 6);   // 0..7
    const int mode = wv >> 2;                    // 0 = G, 1 = M
    const int r0   = (wv & 3) << 4;
    const int moff = (wv & 4);                   // red sub-block base
    const int bid  = (int)blockIdx.x;            // bh*NP + p
    const size_t segbase = (size_t)bid * (SEG * Dd);

    __shared__ float la[CH * 64], lb[CH * 64], lw_[CH * 64];
    __shared__ float lk[CH * 64], lv[CH * 64];
    __shared__ float red[2][8][64];

    float h[16];
#pragma unroll
    for (int r = 0; r < 16; ++r) h[r] = mode ? ((r0 + r == lane) ? 1.f : 0.f) : 0.f;

    for (int c0 = 0; c0 < SEG; c0 += CH) {
        __syncthreads();                          // prior chunk reads done
        {
            const size_t gb = segbase + (size_t)c0 * 64;
            if (tid < CH * 16) {                  // waves 0-3: a, b, exp(gk)
                ((float4*)la)[tid] = ((const float4*)(ap + gb))[tid];
                ((float4*)lb)[tid] = ((const float4*)(bp + gb))[tid];
                float4 g = ((const float4*)(gkp + gb))[tid], e;
                e.x = __expf(g.x); e.y = __expf(g.y);
                e.z = __expf(g.z); e.w = __expf(g.w);
                ((float4*)lw_)[tid] = e;
            } else {                              // waves 4-7: k, v
                const int i2 = tid - CH * 16;
                ((float4*)lk)[i2] = ((const float4*)(kp + gb))[i2];
                ((float4*)lv)[i2] = ((const float4*)(vp + gb))[i2];
            }
        }
        __syncthreads();                          // staging visible

#pragma unroll
        for (int tl = 0; tl < CH; ++tl) {
            const int par = (c0 + tl) & 1;
            // ---- partial a^T h over my 16 rows (broadcast b128 reads)
            const float4* ar = (const float4*)(la + tl * 64 + r0);
            float s0 = 0.f, s1 = 0.f, s2 = 0.f, s3 = 0.f;
#pragma unroll
            for (int jj = 0; jj < 4; ++jj) {
                const float4 a4 = ar[jj];
                s0 = fmaf(a4.x, h[4*jj+0], s0);
                s1 = fmaf(a4.y, h[4*jj+1], s1);
                s2 = fmaf(a4.z, h[4*jj+2], s2);
                s3 = fmaf(a4.w, h[4*jj+3], s3);
            }
            red[par][wv][lane] = (s0 + s1) + (s2 + s3);
            __syncthreads();                      // the ONLY per-step barrier
            const float ah = (red[par][moff + 0][lane] + red[par][moff + 1][lane]) +
                             (red[par][moff + 2][lane] + red[par][moff + 3][lane]);

            const float4* br = (const float4*)(lb  + tl * 64 + r0);
            const float4* wr = (const float4*)(lw_ + tl * 64 + r0);
            if (mode == 0) {                      // wave-uniform branch
                const float u = lv[tl * 64 + lane];
                const float4* kr = (const float4*)(lk + tl * 64 + r0);
#pragma unroll
                for (int jj = 0; jj < 4; ++jj) {
                    const float4 b4 = br[jj], k4 = kr[jj], w4 = wr[jj];
                    h[4*jj+0] = fmaf(w4.x, h[4*jj+0], fmaf(b4.x, ah, k4.x * u));
                    h[4*jj+1] = fmaf(w4.y, h[4*jj+1], fmaf(b4.y, ah, k4.y * u));
                    h[4*jj+2] = fmaf(w4.z, h[4*jj+2], fmaf(b4.z, ah, k4.z * u));
                    h[4*jj+3] = fmaf(w4.w, h[4*jj+3], fmaf(b4.w, ah, k4.w * u));
                }
            } else {
#pragma unroll
                for (int jj = 0; jj < 4; ++jj) {
                    const float4 b4 = br[jj], w4 = wr[jj];
                    h[4*jj+0] = fmaf(w4.x, h[4*jj+0], b4.x * ah);
                    h[4*jj+1] = fmaf(w4.y, h[4*jj+1], b4.y * ah);
                    h[4*jj+2] = fmaf(w4.z, h[4*jj+2], b4.z * ah);
                    h[4*jj+3] = fmaf(w4.w, h[4*jj+3], b4.w * ah);
                }
            }
        }
    }

    const int p  = bid & (NP - 1);
    const int bh = bid / NP;
    float* dst = (mode == 0) ? Gbuf + (size_t)bid * 4096
                             : m_slot(MbufA, MbufB, nplo, bh, p, NP);
#pragma unroll
    for (int r = 0; r < 16; ++r) dst[(r0 + r) * 64 + lane] = h[r];
}

// ---------------------------------------------------------------------------
// Phase 2 (unchanged from round 6): SW_p = M_p * SW_{p-1} + G_p, 4 col-blocks
// per bh; double-buffered reg-staged M with swizzled LDS placement.
// ---------------------------------------------------------------------------
template<int NP>
__global__ __launch_bounds__(256) void combine(
    const float* MbufA, const float* MbufB, int nplo, float* __restrict__ Gbuf)
{
    const int bh  = (int)blockIdx.x >> 2;
    const int cb  = (int)blockIdx.x & 3;
    const int c0  = cb * 16;
    const int tid = (int)threadIdx.x;
    const int cl  = tid & 15;
    const int c   = c0 + cl;
    const int rg  = tid >> 4;            // 0..15
    const int r0  = rg * 4;
    const int xorv = (rg & 1) << 2;

    __shared__ float4 Ml[2][1024];
    __shared__ __align__(16) float swT[16][68];

    {
        const float* G0 = Gbuf + (size_t)bh * NP * 4096;
        for (int i = tid; i < 1024; i += 256)
            swT[i & 15][i >> 4] = G0[(i >> 4) * 64 + c0 + (i & 15)];
    }

    float4 mreg[4];
    if (NP > 1) {
        const float4* Mp = (const float4*)m_slot((float*)MbufA, (float*)MbufB,
                                                 nplo, bh, 1, NP);
#pragma unroll
        for (int j = 0; j < 4; ++j) mreg[j] = Mp[j * 256 + tid];
    }
    __syncthreads();
#pragma unroll
    for (int j = 0; j < 4; ++j) {
        const int f = j * 256 + tid;
        Ml[0][f ^ ((f >> 4) & 4)] = mreg[j];
    }
    if (NP > 2) {
        const float4* Mp = (const float4*)m_slot((float*)MbufA, (float*)MbufB,
                                                 nplo, bh, 2, NP);
#pragma unroll
        for (int j = 0; j < 4; ++j) mreg[j] = Mp[j * 256 + tid];
    }
    __syncthreads();

    for (int p = 1; p < NP; ++p) {
        const int par = (p - 1) & 1;
        float* Gp = Gbuf + ((size_t)bh * NP + p) * 4096;

        float gacc[4];
#pragma unroll
        for (int r = 0; r < 4; ++r) gacc[r] = Gp[(r0 + r) * 64 + c];

        float accA[4] = {0.f, 0.f, 0.f, 0.f};
        float accB[4] = {0.f, 0.f, 0.f, 0.f};
        const float4* swr = (const float4*)&swT[cl][0];
#pragma unroll
        for (int m4 = 0; m4 < 16; ++m4) {
            const float4 s = swr[m4];
            const int ms = m4 ^ xorv;
#pragma unroll
            for (int r = 0; r < 4; ++r) {
                const float4 m = Ml[par][(r0 + r) * 16 + ms];
                accA[r] = fmaf(m.x, s.x, fmaf(m.y, s.y, accA[r]));
                accB[r] = fmaf(m.z, s.z, fmaf(m.w, s.w, accB[r]));
            }
        }
        __syncthreads();

#pragma unroll
        for (int r = 0; r < 4; ++r) {
            const float val = accA[r] + accB[r] + gacc[r];
            swT[cl][r0 + r] = val;
            Gp[(r0 + r) * 64 + c] = val;
        }
        if (p + 1 < NP) {
#pragma unroll
            for (int j = 0; j < 4; ++j) {
                const int f = j * 256 + tid;
                Ml[par ^ 1][f ^ ((f >> 4) & 4)] = mreg[j];
            }
        }
        if (p + 2 < NP) {
            const float4* Mp = (const float4*)m_slot((float*)MbufA, (float*)MbufB,
                                                     nplo, bh, p + 2, NP);
#pragma unroll
            for (int j = 0; j < 4; ++j) mreg[j] = Mp[j * 256 + tid];
        }
        __syncthreads();
    }
}

// ---------------------------------------------------------------------------
// Phase 3: replay segment p from SW_{p-1}; o_t = h_t^T q_t -> d_out [B,S,hid].
// 256 thr = 4 waves, 16 rows each; step loop fully unrolled; deferred-parity
// o reduction shares the single per-step barrier.
// ---------------------------------------------------------------------------
template<int SEG, int CH>
__global__ __launch_bounds__(256, 6) void scan_out(
    const float* __restrict__ qp, const float* __restrict__ kp,
    const float* __restrict__ vp, const float* __restrict__ ap,
    const float* __restrict__ bp, const float* __restrict__ gkp,
    const float* __restrict__ Gbuf, float* __restrict__ out)
{
    constexpr int NP = Ss / SEG;
    const int tid  = (int)threadIdx.x;
    const int lane = tid & 63;
    const int w    = __builtin_amdgcn_readfirstlane(tid >> 6);   // 0..3
    const int r0   = w << 4;
    const int bid  = (int)blockIdx.x;            // bh*NP + p
    const int p    = bid & (NP - 1);
    const int bh   = bid / NP;
    const int b    = bh >> 5, hh = bh & (Hh - 1);
    const size_t segbase = (size_t)bid * (SEG * Dd);

    __shared__ float la[CH * 64], lb[CH * 64], lw_[CH * 64];
    __shared__ float lk[CH * 64], lv[CH * 64], lq[CH * 64];
    __shared__ float red_a[2][4][64];
    __shared__ float red_o[2][4][64];

    float h[16];
    if (p) {
        const float* sw = Gbuf + (size_t)(bid - 1) * 4096;
#pragma unroll
        for (int r = 0; r < 16; ++r) h[r] = sw[(r0 + r) * 64 + lane];
    } else {
#pragma unroll
        for (int r = 0; r < 16; ++r) h[r] = 0.f;
    }

    for (int c0 = 0; c0 < SEG; c0 += CH) {
        __syncthreads();
        {
            const size_t gb = segbase + (size_t)c0 * 64;
            for (int i = tid; i < CH * 16; i += 256) {
                ((float4*)la)[i] = ((const float4*)(ap + gb))[i];
                ((float4*)lb)[i] = ((const float4*)(bp + gb))[i];
                float4 g = ((const float4*)(gkp + gb))[i], e;
                e.x = __expf(g.x); e.y = __expf(g.y);
                e.z = __expf(g.z); e.w = __expf(g.w);
                ((float4*)lw_)[i] = e;
                ((float4*)lk)[i] = ((const float4*)(kp + gb))[i];
                ((float4*)lv)[i] = ((const float4*)(vp + gb))[i];
                ((float4*)lq)[i] = ((const float4*)(qp + gb))[i];
            }
        }
        __syncthreads();

#pragma unroll
        for (int tl = 0; tl < CH; ++tl) {
            const int t = c0 + tl;
            const int par = t & 1;
            const float4* ar = (const float4*)(la + tl * 64 + r0);
            float s0 = 0.f, s1 = 0.f, s2 = 0.f, s3 = 0.f;
#pragma unroll
            for (int jj = 0; jj < 4; ++jj) {
                const float4 a4 = ar[jj];
                s0 = fmaf(a4.x, h[4*jj+0], s0);
                s1 = fmaf(a4.y, h[4*jj+1], s1);
                s2 = fmaf(a4.z, h[4*jj+2], s2);
                s3 = fmaf(a4.w, h[4*jj+3], s3);
            }
            red_a[par][w][lane] = (s0 + s1) + (s2 + s3);
            __syncthreads();                      // the ONLY per-step barrier
            const float ah = (red_a[par][0][lane] + red_a[par][1][lane]) +
                             (red_a[par][2][lane] + red_a[par][3][lane]);

            if (w == 0 && t > 0) {                // deferred o_{t-1} store
                const int pe = par ^ 1;
                const float os = (red_o[pe][0][lane] + red_o[pe][1][lane]) +
                                 (red_o[pe][2][lane] + red_o[pe][3][lane]);
                const int s = p * SEG + t - 1;
                out[(((size_t)b * Ss + s) * Hh + hh) * Dd + lane] = os;
            }

            const float u = lv[tl * 64 + lane];
            const float4* br = (const float4*)(lb  + tl * 64 + r0);
            const float4* kr = (const float4*)(lk  + tl * 64 + r0);
            const float4* wr = (const float4*)(lw_ + tl * 64 + r0);
            const float4* qr = (const float4*)(lq  + tl * 64 + r0);
            float o0 = 0.f, o1 = 0.f, o2 = 0.f, o3 = 0.f;
#pragma unroll
            for (int jj = 0; jj < 4; ++jj) {
                const float4 b4 = br[jj], k4 = kr[jj], w4 = wr[jj], q4 = qr[jj];
                h[4*jj+0] = fmaf(w4.x, h[4*jj+0], fmaf(b4.x, ah, k4.x * u));
                o0 = fmaf(q4.x, h[4*jj+0], o0);
                h[4*jj+1] = fmaf(w4.y, h[4*jj+1], fmaf(b4.y, ah, k4.y * u));
                o1 = fmaf(q4.y, h[4*jj+1], o1);
                h[4*jj+2] = fmaf(w4.z, h[4*jj+2], fmaf(b4.z, ah, k4.z * u));
                o2 = fmaf(q4.z, h[4*jj+2], o2);
                h[4*jj+3] = fmaf(w4.w, h[4*jj+3], fmaf(b4.w, ah, k4.w * u));
                o3 = fmaf(q4.w, h[4*jj+3], o3);
            }
            red_o[par][w][lane] = (o0 + o1) + (o2 + o3);
        }
    }

    __syncthreads();
    if (w == 0) {                                // tail: o_{SEG-1}
        const int pe = (SEG - 1) & 1;
        const float os = (red_o[pe][0][lane] + red_o[pe][1][lane]) +
                         (red_o[pe][2][lane] + red_o[pe][3][lane]);
        const int s = p * SEG + SEG - 1;
        out[(((size_t)b * Ss + s) * Hh + hh) * Dd + lane] = os;
    }
}

// ---------------------------------------------------------------------------
// Epilogue (unchanged): in-place GroupNorm + correction + gate on d_out.
// ---------------------------------------------------------------------------
__global__ __launch_bounds__(256) void epilogue(
    const float* __restrict__ qp, const float* __restrict__ kp,
    const float* __restrict__ vp, const float* __restrict__ rk,
    const float* __restrict__ gp, const float* __restrict__ sc,
    const float* __restrict__ bi, float* __restrict__ out)
{
    const int lane = (int)(threadIdx.x & 63u);
    const int gid  = (int)blockIdx.x * 4 + (int)(threadIdx.x >> 6);
    const int hh   = gid & (Hh - 1);
    const int bs   = gid >> 5;
    const int b    = bs >> 10;
    const int s    = bs & (Ss - 1);

    const size_t ioff = ((size_t)(b * Hh + hh) * Ss + s) * Dd + lane;
    const float qv = qp[ioff];
    const float kv = kp[ioff];
    const float vv = vp[ioff];
    const float r  = rk[hh * Dd + lane];

    const size_t goff = (size_t)bs * (Hh * Dd) + hh * Dd + lane;
    const float o = out[goff];

    float s1 = o, s2 = o * o, s3 = qv * kv * r;
#pragma unroll
    for (int m = 32; m >= 1; m >>= 1) {
        s1 += __shfl_xor(s1, m, 64);
        s2 += __shfl_xor(s2, m, 64);
        s3 += __shfl_xor(s3, m, 64);
    }
    const float mu  = s1 * (1.f / 64.f);
    const float var = fmaf(-mu, mu, s2 * (1.f / 64.f));
    const float on  = (o - mu) * rsqrtf(var + 1e-5f);

    out[goff] = (fmaf(on, sc[hh * Dd + lane], bi[hh * Dd + lane]) + s3 * vv) * gp[goff];
}

// ---------------------------------------------------------------------------
extern "C" void kernel_launch(void* const* d_in, const int* in_sizes, int n_in,
                              void* d_out, int out_size, void* d_ws, size_t ws_size,
                              hipStream_t stream)
{
    const float* q   = (const float*)d_in[0];
    const float* k   = (const float*)d_in[1];
    const float* v   = (const float*)d_in[2];
    const float* a   = (const float*)d_in[3];
    const float* b   = (const float*)d_in[4];
    const float* gk  = (const float*)d_in[5];
    const float* r_k = (const float*)d_in[6];
    const float* g   = (const float*)d_in[7];
    const float* gns = (const float*)d_in[8];
    const float* gnb = (const float*)d_in[9];
    float* out = (float*)d_out;
    float* ws  = (float*)d_ws;

    const size_t slotf   = 4096;
    const size_t g32     = (size_t)NBH * 32 * slotf;
    const size_t need32  = g32 * 4 * 2;                              // 64 MiB
    const size_t need32b = g32 * 4 + (size_t)NBH * 16 * slotf * 4;   // 48 MiB

    if (ws_size >= need32) {
        float* G  = ws;
        float* MA = ws + g32;
        scan_seg_fused<32,16><<<dim3(NBH * 32), dim3(512), 0, stream>>>(k, v, a, b, gk, G, MA, MA, 32);
        combine<32><<<dim3(NBH * 4), dim3(256), 0, stream>>>(MA, MA, 32, G);
        scan_out<32,16><<<dim3(NBH * 32), dim3(256), 0, stream>>>(q, k, v, a, b, gk, G, out);
    } else if (ws_size >= need32b) {
        float* G  = ws;
        float* MA = out;
        float* MB = ws + g32;
        scan_seg_fused<32,16><<<dim3(NBH * 32), dim3(512), 0, stream>>>(k, v, a, b, gk, G, MA, MB, 16);
        combine<32><<<dim3(NBH * 4), dim3(256), 0, stream>>>(MA, MB, 16, G);
        scan_out<32,16><<<dim3(NBH * 32), dim3(256), 0, stream>>>(q, k, v, a, b, gk, G, out);
    } else {
        float* G  = ws;
        float* MA = out;
        scan_seg_fused<64,16><<<dim3(NBH * 16), dim3(512), 0, stream>>>(k, v, a, b, gk, G, MA, MA, 16);
        combine<16><<<dim3(NBH * 4), dim3(256), 0, stream>>>(MA, MA, 16, G);
        scan_out<64,16><<<dim3(NBH * 16), dim3(256), 0, stream>>>(q, k, v, a, b, gk, G, out);
    }

    epilogue<<<dim3(Bb * Ss * Hh / 4), dim3(256), 0, stream>>>(
        q, k, v, r_k, g, gns, gnb, out);
}